// Round 1
// baseline (989.091 us; speedup 1.0000x reference)
//
#include <hip/hip_runtime.h>
#include <math.h>

#define NN 50000
#define DD 128
#define NCLS 40
#define EPSV 1e-8f

__device__ __forceinline__ float waveReduceSum(float v) {
    for (int off = 32; off > 0; off >>= 1) v += __shfl_xor(v, off, 64);
    return v;
}

// x = expmap0(node_feat): in (N,127) -> out (N,128)
__global__ void expmap_kernel(const float* __restrict__ nf, float* __restrict__ out, int n) {
    int wid = threadIdx.x >> 6, lane = threadIdx.x & 63;
    for (int row = blockIdx.x * 4 + wid; row < n; row += gridDim.x * 4) {
        const float* r = nf + (long)row * 127;
        float e0 = r[lane];                                  // idx 0..63 < 127 always
        float e1 = (lane < 63) ? r[lane + 64] : 0.f;         // idx 64..126
        float ss = waveReduceSum(e0 * e0 + e1 * e1);
        float nrm = fmaxf(sqrtf(ss), EPSV);
        float ex = expf(nrm), exn = 1.f / ex;
        float ch = 0.5f * (ex + exn);
        float coef = (0.5f * (ex - exn)) / nrm;
        float* o = out + (long)row * 128;
        if (lane == 0) o[0] = ch;
        o[lane + 1] = coef * e0;
        if (lane < 63) o[lane + 65] = coef * e1;
    }
}

// out = lorentz_linear( [prenorm+relu?](X), W, b, logs )
template <int PRENORM, int RELU>
__global__ __launch_bounds__(256, 2) void linear_lorentz(
    const float* __restrict__ X, const float* __restrict__ W,
    const float* __restrict__ bias, const float* __restrict__ logs,
    float* __restrict__ out, int n)
{
    __shared__ float Wt[128 * 129];   // transposed, stride 129 (conflict-free)
    __shared__ float bs[128];
    __shared__ float xrow[4][128];
    int tid = threadIdx.x;
    for (int idx = tid; idx < 128 * 128; idx += 256) {
        int i = idx >> 7, k = idx & 127;
        Wt[k * 129 + i] = W[idx];
    }
    if (tid < 128) bs[tid] = bias[tid];
    __syncthreads();
    float sval = fminf(expf(logs[0]), 10.f);
    int wid = tid >> 6, lane = tid & 63;
    for (int row0 = blockIdx.x * 4; row0 < n; row0 += gridDim.x * 4) {
        int row = row0 + wid;
        bool active = row < n;
        float e0 = 0.f, e1 = 0.f;
        if (active) {
            e0 = X[(long)row * 128 + lane];
            e1 = X[(long)row * 128 + 64 + lane];
        }
        if (PRENORM) {
            float s0 = __shfl(e0, 0, 64);
            float ss = waveReduceSum(e0 * e0 + e1 * e1);
            float neg_inner = 2.f * s0 * s0 - ss;
            float inv = 1.f / sqrtf(fmaxf(fabsf(neg_inner), EPSV));
            e0 *= inv; e1 *= inv;
        }
        if (RELU) { e0 = fmaxf(e0, 0.f); e1 = fmaxf(e1, 0.f); }
        xrow[wid][lane] = e0;
        xrow[wid][lane + 64] = e1;
        __syncthreads();
        float acc0 = 0.f, acc1 = 0.f;
        #pragma unroll 8
        for (int k = 0; k < 128; ++k) {
            float xk = xrow[wid][k];
            acc0 = fmaf(xk, Wt[k * 129 + lane], acc0);
            acc1 = fmaf(xk, Wt[k * 129 + 64 + lane], acc1);
        }
        acc0 += bs[lane]; acc1 += bs[lane + 64];
        float t0 = __shfl(acc0, 0, 64);
        float ssq = waveReduceSum(acc0 * acc0 + acc1 * acc1);
        float timev = sval / (1.f + expf(-t0)) + 1.5f;
        float sq = fmaxf(ssq - t0 * t0, EPSV);
        float fac = sqrtf(fmaxf((timev * timev - 1.f) / sq, EPSV));
        if (active) {
            out[(long)row * 128 + lane] = (lane == 0) ? timev : acc0 * fac;
            out[(long)row * 128 + 64 + lane] = acc1 * fac;
        }
        __syncthreads();
    }
}

// S[erow[e]] += X[ecol[e]] * ew[e]   (atomic)
__global__ void scatter_kernel(const float* __restrict__ X, const float* __restrict__ ew,
                               const int* __restrict__ erow, const int* __restrict__ ecol,
                               float* __restrict__ S, int E)
{
    int wid = threadIdx.x >> 6, lane = threadIdx.x & 63;
    for (int e = blockIdx.x * 4 + wid; e < E; e += gridDim.x * 4) {
        int col = ecol[e], rw = erow[e];
        float w = ew[e];
        float v0 = X[(long)col * 128 + lane] * w;
        float v1 = X[(long)col * 128 + 64 + lane] * w;
        atomicAdd(&S[(long)rw * 128 + lane], v0);
        atomicAdd(&S[(long)rw * 128 + 64 + lane], v1);
    }
}

// normalize (lorentz denom), sign-flip time, logits = 2 + 2*(xs @ cls^T) + cb
__global__ void logits_kernel(const float* __restrict__ Sv, const float* __restrict__ cls,
                              const float* __restrict__ cbias, float* __restrict__ outp, int n)
{
    int wid = threadIdx.x >> 6, lane = threadIdx.x & 63;
    for (int row = blockIdx.x * 4 + wid; row < n; row += gridDim.x * 4) {
        float s0v = Sv[(long)row * 128 + lane];
        float s1v = Sv[(long)row * 128 + 64 + lane];
        float t0 = __shfl(s0v, 0, 64);
        float ss = waveReduceSum(s0v * s0v + s1v * s1v);
        float neg_inner = 2.f * t0 * t0 - ss;
        float inv = 1.f / sqrtf(fmaxf(fabsf(neg_inner), EPSV));
        float x0 = s0v * inv, x1 = s1v * inv;
        if (lane == 0) x0 = -x0;
        float res = 0.f;
        for (int c = 0; c < NCLS; ++c) {
            float p = x0 * cls[c * 128 + lane] + x1 * cls[c * 128 + 64 + lane];
            p = waveReduceSum(p);
            if (lane == c) res = p;
        }
        if (lane < NCLS) outp[(long)row * 40 + lane] = 2.f + 2.f * res + cbias[lane];
    }
}

extern "C" void kernel_launch(void* const* d_in, const int* in_sizes, int n_in,
                              void* d_out, int out_size, void* d_ws, size_t ws_size,
                              hipStream_t stream) {
    const float* node_feat = (const float*)d_in[0];
    const float* W1   = (const float*)d_in[1];
    const float* b1   = (const float*)d_in[2];
    const float* s1   = (const float*)d_in[3];
    const float* W2   = (const float*)d_in[4];
    const float* b2   = (const float*)d_in[5];
    const float* s2   = (const float*)d_in[6];
    const float* cls  = (const float*)d_in[7];
    const float* cb   = (const float*)d_in[8];
    const float* ew   = (const float*)d_in[9];
    const int*   erow = (const int*)d_in[10];
    const int*   ecol = (const int*)d_in[11];
    float* outp = (float*)d_out;

    const size_t nodeBytes = (size_t)NN * DD * sizeof(float);
    float* bufA = (float*)d_ws;
    float* bufB = (float*)((char*)d_ws + nodeBytes);

    const int E = in_sizes[9];
    const int n = NN;

    // 1. expmap0 -> bufA
    expmap_kernel<<<2048, 256, 0, stream>>>(node_feat, bufA, n);
    // 2. linear1 (no prenorm, no relu) -> bufB
    linear_lorentz<0, 0><<<512, 256, 0, stream>>>(bufA, W1, b1, s1, bufB, n);
    // 3. agg1: zero bufA, scatter bufB -> bufA
    hipMemsetAsync(bufA, 0, nodeBytes, stream);
    scatter_kernel<<<2048, 256, 0, stream>>>(bufB, ew, erow, ecol, bufA, E);
    // 4. linear2 (prenorm + relu) -> bufB
    linear_lorentz<1, 1><<<512, 256, 0, stream>>>(bufA, W2, b2, s2, bufB, n);
    // 5. agg2: zero bufA, scatter bufB -> bufA
    hipMemsetAsync(bufA, 0, nodeBytes, stream);
    scatter_kernel<<<2048, 256, 0, stream>>>(bufB, ew, erow, ecol, bufA, E);
    // 6. normalize + logits
    logits_kernel<<<2048, 256, 0, stream>>>(bufA, cls, cb, outp, n);
}

// Round 2
// 448.867 us; speedup vs baseline: 2.2035x; 2.2035x over previous
//
#include <hip/hip_runtime.h>
#include <math.h>

#define NN 50000
#define DD 128
#define NCLS 40
#define EPSV 1e-8f

__device__ __forceinline__ float waveReduceSum(float v) {
    for (int off = 32; off > 0; off >>= 1) v += __shfl_xor(v, off, 64);
    return v;
}

// ---------------- CSR build ----------------

__global__ void hist_kernel(const int* __restrict__ erow, int* __restrict__ cnt, int E) {
    for (int e = blockIdx.x * blockDim.x + threadIdx.x; e < E; e += gridDim.x * blockDim.x)
        atomicAdd(&cnt[erow[e]], 1);
}

// per-block exclusive scan of 256 elements + block sums
__global__ void scan1_kernel(const int* __restrict__ cnt, int* __restrict__ rs,
                             int* __restrict__ bsum, int n) {
    __shared__ int sdata[256];
    int tid = threadIdx.x;
    int gid = blockIdx.x * 256 + tid;
    int v = (gid < n) ? cnt[gid] : 0;
    sdata[tid] = v;
    __syncthreads();
    for (int off = 1; off < 256; off <<= 1) {
        int t = (tid >= off) ? sdata[tid - off] : 0;
        __syncthreads();
        sdata[tid] += t;
        __syncthreads();
    }
    if (gid < n) rs[gid] = sdata[tid] - v;            // exclusive, block-local
    if (tid == 255) bsum[blockIdx.x] = sdata[255];    // block total
}

// scan block sums (nb <= 256), in place -> exclusive
__global__ void scan2_kernel(int* __restrict__ bsum, int nb) {
    __shared__ int sdata[256];
    int tid = threadIdx.x;
    int v = (tid < nb) ? bsum[tid] : 0;
    sdata[tid] = v;
    __syncthreads();
    for (int off = 1; off < 256; off <<= 1) {
        int t = (tid >= off) ? sdata[tid - off] : 0;
        __syncthreads();
        sdata[tid] += t;
        __syncthreads();
    }
    if (tid < nb) bsum[tid] = sdata[tid] - v;         // exclusive
}

__global__ void scan3_kernel(int* __restrict__ rs, const int* __restrict__ bsum, int n, int E) {
    int gid = blockIdx.x * 256 + threadIdx.x;
    if (gid < n) rs[gid] += bsum[blockIdx.x];
    else if (gid == n) rs[n] = E;
}

__global__ void fill_kernel(const int* __restrict__ erow, const int* __restrict__ ecol,
                            const float* __restrict__ ew, int* __restrict__ pos,
                            int* __restrict__ ecol_s, float* __restrict__ ew_s, int E) {
    for (int e = blockIdx.x * blockDim.x + threadIdx.x; e < E; e += gridDim.x * blockDim.x) {
        int r = erow[e];
        int p = atomicAdd(&pos[r], 1);
        ecol_s[p] = ecol[e];
        ew_s[p] = ew[e];
    }
}

// ---------------- fused linears ----------------
// PREEXP=1: X is node_feat (N,127); apply expmap0 first. No prenorm/relu.
// PREEXP=0: X is (N,128) raw agg sums; apply lorentz-normalize + relu first.
template <int PREEXP>
__global__ __launch_bounds__(256, 2) void linear_lorentz(
    const float* __restrict__ X, const float* __restrict__ W,
    const float* __restrict__ bias, const float* __restrict__ logs,
    float* __restrict__ out, int n)
{
    __shared__ float Wt[128 * 128];   // Wt[k][i] = W[i][k]; float2 reads, 2-way (free)
    __shared__ float bs[128];
    __shared__ float xrow[4][128];
    int tid = threadIdx.x;
    for (int idx = tid; idx < 128 * 128; idx += 256) {
        int i = idx >> 7, k = idx & 127;
        Wt[k * 128 + i] = W[idx];
    }
    if (tid < 128) bs[tid] = bias[tid];
    __syncthreads();
    float sval = fminf(expf(logs[0]), 10.f);
    int wid = tid >> 6, lane = tid & 63;
    float* xr = xrow[wid];
    for (int row = blockIdx.x * 4 + wid; row < n; row += gridDim.x * 4) {
        if (PREEXP) {
            const float* r = X + (long)row * 127;
            float u0 = r[2 * lane];                              // 2*lane <= 126
            float u1 = (2 * lane + 1 < 127) ? r[2 * lane + 1] : 0.f;
            float ss = waveReduceSum(u0 * u0 + u1 * u1);
            float nrm = fmaxf(sqrtf(ss), EPSV);
            float ex = expf(nrm), exn = 1.f / ex;
            float ch = 0.5f * (ex + exn);
            float coef = (0.5f * (ex - exn)) / nrm;
            if (lane == 0) xr[0] = ch;
            xr[1 + 2 * lane] = coef * u0;
            if (2 * lane + 1 < 127) xr[2 + 2 * lane] = coef * u1;
        } else {
            float2 e = *(const float2*)(X + (long)row * 128 + 2 * lane);
            float t0 = __shfl(e.x, 0, 64);
            float ss = waveReduceSum(e.x * e.x + e.y * e.y);
            float neg_inner = 2.f * t0 * t0 - ss;
            float inv = 1.f / sqrtf(fmaxf(fabsf(neg_inner), EPSV));
            e.x = fmaxf(e.x * inv, 0.f);
            e.y = fmaxf(e.y * inv, 0.f);
            *(float2*)(xr + 2 * lane) = e;
        }
        // xrow is wave-private: no barrier needed (lgkmcnt ordering within wave)
        float2 acc = {0.f, 0.f};
        #pragma unroll 8
        for (int k = 0; k < 128; ++k) {
            float xk = xr[k];
            float2 wv = *(const float2*)(Wt + k * 128 + 2 * lane);
            acc.x = fmaf(xk, wv.x, acc.x);
            acc.y = fmaf(xk, wv.y, acc.y);
        }
        acc.x += bs[2 * lane];
        acc.y += bs[2 * lane + 1];
        float t0 = __shfl(acc.x, 0, 64);
        float ssq = waveReduceSum(acc.x * acc.x + acc.y * acc.y);
        float timev = sval / (1.f + expf(-t0)) + 1.5f;
        float sq = fmaxf(ssq - t0 * t0, EPSV);
        float fac = sqrtf(fmaxf((timev * timev - 1.f) / sq, EPSV));
        float2 o;
        o.x = (lane == 0) ? timev : acc.x * fac;
        o.y = acc.y * fac;
        *(float2*)(out + (long)row * 128 + 2 * lane) = o;
    }
}

// ---------------- CSR gather (agg) ----------------

__global__ void gather_kernel(const float* __restrict__ X, const int* __restrict__ rs,
                              const int* __restrict__ ecol_s, const float* __restrict__ ew_s,
                              float* __restrict__ S, int n)
{
    int wid = threadIdx.x >> 6, lane = threadIdx.x & 63;
    for (int row = blockIdx.x * 4 + wid; row < n; row += gridDim.x * 4) {
        int beg = rs[row], end = rs[row + 1];
        float2 acc = {0.f, 0.f};
        for (int base = beg; base < end; base += 64) {
            int idx = base + lane;
            int colv = (idx < end) ? ecol_s[idx] : 0;
            float wv = (idx < end) ? ew_s[idx] : 0.f;
            int cnt = min(64, end - base);
            for (int j = 0; j < cnt; ++j) {
                int c = __shfl(colv, j, 64);
                float wj = __shfl(wv, j, 64);
                float2 xv = *(const float2*)(X + (long)c * 128 + 2 * lane);
                acc.x = fmaf(wj, xv.x, acc.x);
                acc.y = fmaf(wj, xv.y, acc.y);
            }
        }
        *(float2*)(S + (long)row * 128 + 2 * lane) = acc;
    }
}

// agg2 + lorentz-normalize + sign-flip + logits, fused
__global__ void gather_logits_kernel(
    const float* __restrict__ X, const int* __restrict__ rs,
    const int* __restrict__ ecol_s, const float* __restrict__ ew_s,
    const float* __restrict__ cls, const float* __restrict__ cbias,
    float* __restrict__ outp, int n)
{
    __shared__ float clsS[NCLS * 129];   // stride 129: class loop conflict-free
    __shared__ float cbS[NCLS];
    __shared__ float xsrow[4][128];
    int tid = threadIdx.x;
    for (int idx = tid; idx < NCLS * 128; idx += 256) {
        int c = idx >> 7, k = idx & 127;
        clsS[c * 129 + k] = cls[idx];
    }
    if (tid < NCLS) cbS[tid] = cbias[tid];
    __syncthreads();
    int wid = tid >> 6, lane = tid & 63;
    float* xs = xsrow[wid];
    for (int row = blockIdx.x * 4 + wid; row < n; row += gridDim.x * 4) {
        int beg = rs[row], end = rs[row + 1];
        float2 acc = {0.f, 0.f};
        for (int base = beg; base < end; base += 64) {
            int idx = base + lane;
            int colv = (idx < end) ? ecol_s[idx] : 0;
            float wv = (idx < end) ? ew_s[idx] : 0.f;
            int cnt = min(64, end - base);
            for (int j = 0; j < cnt; ++j) {
                int c = __shfl(colv, j, 64);
                float wj = __shfl(wv, j, 64);
                float2 xv = *(const float2*)(X + (long)c * 128 + 2 * lane);
                acc.x = fmaf(wj, xv.x, acc.x);
                acc.y = fmaf(wj, xv.y, acc.y);
            }
        }
        float t0 = __shfl(acc.x, 0, 64);
        float ss = waveReduceSum(acc.x * acc.x + acc.y * acc.y);
        float neg_inner = 2.f * t0 * t0 - ss;
        float inv = 1.f / sqrtf(fmaxf(fabsf(neg_inner), EPSV));
        float2 xv;
        xv.x = acc.x * inv;
        xv.y = acc.y * inv;
        if (lane == 0) xv.x = -xv.x;
        xs[2 * lane] = xv.x;
        xs[2 * lane + 1] = xv.y;
        // wave-private LDS; lane-per-class dot
        if (lane < NCLS) {
            float dot = 0.f;
            #pragma unroll 8
            for (int k = 0; k < 128; ++k)
                dot = fmaf(xs[k], clsS[lane * 129 + k], dot);
            outp[(long)row * NCLS + lane] = 2.f + 2.f * dot + cbS[lane];
        }
    }
}

// ---------------- launch ----------------

extern "C" void kernel_launch(void* const* d_in, const int* in_sizes, int n_in,
                              void* d_out, int out_size, void* d_ws, size_t ws_size,
                              hipStream_t stream) {
    const float* node_feat = (const float*)d_in[0];
    const float* W1   = (const float*)d_in[1];
    const float* b1   = (const float*)d_in[2];
    const float* s1   = (const float*)d_in[3];
    const float* W2   = (const float*)d_in[4];
    const float* b2   = (const float*)d_in[5];
    const float* s2   = (const float*)d_in[6];
    const float* cls  = (const float*)d_in[7];
    const float* cb   = (const float*)d_in[8];
    const float* ew   = (const float*)d_in[9];
    const int*   erow = (const int*)d_in[10];
    const int*   ecol = (const int*)d_in[11];
    float* outp = (float*)d_out;

    const int n = NN;
    const int E = in_sizes[9];
    const int NBLK = (NN + 255) / 256;   // 196

    float* bufA   = (float*)d_ws;                       // NN*128
    float* bufB   = bufA + (size_t)NN * 128;            // NN*128
    int*   rs     = (int*)(bufB + (size_t)NN * 128);    // NN+1
    int*   pos    = rs + (NN + 1);                      // NN  (counts, then fill cursor)
    int*   bsum   = pos + NN;                           // NBLK (<=256)
    int*   ecol_s = bsum + 256;                         // E
    float* ew_s   = (float*)(ecol_s + E);               // E

    // CSR build
    hipMemsetAsync(pos, 0, (size_t)NN * sizeof(int), stream);
    hist_kernel<<<2048, 256, 0, stream>>>(erow, pos, E);
    scan1_kernel<<<NBLK, 256, 0, stream>>>(pos, rs, bsum, n);
    scan2_kernel<<<1, 256, 0, stream>>>(bsum, NBLK);
    scan3_kernel<<<NBLK, 256, 0, stream>>>(rs, bsum, n, E);
    hipMemcpyAsync(pos, rs, (size_t)NN * sizeof(int), hipMemcpyDeviceToDevice, stream);
    fill_kernel<<<2048, 256, 0, stream>>>(erow, ecol, ew, pos, ecol_s, ew_s, E);

    // pipeline
    linear_lorentz<1><<<512, 256, 0, stream>>>(node_feat, W1, b1, s1, bufA, n);  // expmap+L1
    gather_kernel<<<4096, 256, 0, stream>>>(bufA, rs, ecol_s, ew_s, bufB, n);    // agg1
    linear_lorentz<0><<<512, 256, 0, stream>>>(bufB, W2, b2, s2, bufA, n);       // norm+relu+L2
    gather_logits_kernel<<<4096, 256, 0, stream>>>(bufA, rs, ecol_s, ew_s, cls, cb, outp, n); // agg2+logits
}